// Round 11
// baseline (320.237 us; speedup 1.0000x reference)
//
#include <hip/hip_runtime.h>
#include <cmath>

// SimplifiedSSM: B=2, L=2048, d_model=768, d_state=16, d_inner=1536
// ROUND 25: R24 with the workspace alias FIXED: xpT moved 184320 -> 331776.
// (R24's NaN: prep still writes the legacy f32 xproj copy at bytes
// [135168,331776), which overlapped xpT at 184320 — corrupted bf16 panel.)
// (1) xproj fused into dt GEMM as 32 extra N cols (EPI=4, grid y=25, tail
// clamped; col<1536 softplus bf16 dlt, 1536<=col<1568 f32 BC).
// (2) scan packing 4 d per thread (uint2 loads, shared Bv/Cv, DPP reduce).
#define DMODEL 768
#define DINNER 1536
#define NSTATE 16
#define SEQL   2048
#define NCHUNK 32
#define CHLEN  64      // SEQL / NCHUNK

#define DT_F32  0
#define DT_BF16 1
#define DT_ZERO 2

typedef __bf16 bf16x8 __attribute__((ext_vector_type(8)));
typedef float  f32x4  __attribute__((ext_vector_type(4)));

typedef __attribute__((address_space(3))) unsigned short lds_us;
typedef const __attribute__((address_space(1))) unsigned short glob_us;

__device__ __forceinline__ void async_cp16(glob_us* g, lds_us* l) {
    __builtin_amdgcn_global_load_lds((const __attribute__((address_space(1))) void*)g,
                                     (__attribute__((address_space(3))) void*)l, 16, 0, 0);
}

__device__ __forceinline__ float bf2f(unsigned short h) {
    union { unsigned u; float f; } v; v.u = ((unsigned)h) << 16; return v.f;
}
__device__ __forceinline__ float bflo(unsigned p) {
    union { unsigned u; float f; } v; v.u = p << 16; return v.f;
}
__device__ __forceinline__ float bfhi(unsigned p) {
    union { unsigned u; float f; } v; v.u = p & 0xFFFF0000u; return v.f;
}
__device__ __forceinline__ unsigned short f2bf(float f) {
    union { float f; unsigned u; } v; v.f = f;
    unsigned r = (v.u + 0x7FFFu + ((v.u >> 16) & 1u)) >> 16;
    return (unsigned short)r;
}
// butterfly sum over 4-lane quads via DPP (all lanes get the total)
__device__ __forceinline__ float quad_reduce(float y) {
    int yi = __float_as_int(y);
    y += __int_as_float(__builtin_amdgcn_mov_dpp(yi, 0xB1, 0xF, 0xF, true)); // quad_perm [1,0,3,2]
    yi = __float_as_int(y);
    y += __int_as_float(__builtin_amdgcn_mov_dpp(yi, 0x4E, 0xF, 0xF, true)); // quad_perm [2,3,0,1]
    return y;
}
__device__ int detect_dtype(const void* p) {
    const unsigned* u = (const unsigned*)p;
    int nzlo = 0, band = 0, anynz = 0;
    for (int i = 0; i < 64; ++i) {
        unsigned w = u[i];
        anynz |= (w != 0);
        unsigned lo = w & 0xFFFFu;
        if (lo) {
            ++nzlo;
            unsigned e8 = (lo >> 7) & 0xFF;
            if (e8 >= 0x60 && e8 <= 0x8E) ++band;
        }
    }
    if (nzlo >= 8) return (band * 2 > nzlo) ? DT_BF16 : DT_F32;
    return anynz ? DT_F32 : DT_ZERO;
}
__device__ __forceinline__ float LD(const void* p, size_t i, int dt) {
    if (dt == DT_BF16) return bf2f(((const unsigned short*)p)[i]);
    if (dt == DT_F32)  return ((const float*)p)[i];
    return 0.f;
}

// ---- fused prep: params->f32 (A_log -> A2, conv_w -> 3 planes) | x->bf16 |
//      3 weight transposes | xproj -> bf16 transpose [32][1536] ----
// blocks: [0,324) params, [324,1860) x (8 elem/thread),
//         [1860,2436) in_w, [2436,3012) dt_w, [3012,3300) out_w (64x64 tiles),
//         [3300,3306) xpT
__global__ __launch_bounds__(256) void prep_kernel(
    const void* __restrict__ x, const void* __restrict__ in_w,
    const void* __restrict__ cw, const void* __restrict__ cb,
    const void* __restrict__ xp, const void* __restrict__ dt_w,
    const void* __restrict__ db, const void* __restrict__ Al,
    const void* __restrict__ Dv, const void* __restrict__ out_w,
    unsigned short* __restrict__ xb, unsigned short* __restrict__ inT,
    unsigned short* __restrict__ dtT, unsigned short* __restrict__ outT,
    unsigned short* __restrict__ xpT, float* __restrict__ pf)
{
    __shared__ unsigned short tile[64][68];
    __shared__ int dts[6];
    const int blk = blockIdx.x;
    const int t   = threadIdx.x;

    if (blk < 324) {
        if (t == 0) {
            dts[0] = detect_dtype(cw); dts[1] = detect_dtype(cb);
            dts[2] = detect_dtype(db); dts[3] = detect_dtype(Al);
            dts[4] = detect_dtype(Dv); dts[5] = detect_dtype(xp);
        }
        __syncthreads();
        int g = blk * 256 + t;
        if (g >= 82944) return;
        const void* src; int local; int which;
        if      (g <  4608) { src = cw; local = g;         which = 0; }
        else if (g <  6144) { src = cb; local = g - 4608;  which = 1; }
        else if (g <  7680) { src = db; local = g - 6144;  which = 2; }
        else if (g < 32256) { src = Al; local = g - 7680;  which = 3; }
        else if (g < 33792) { src = Dv; local = g - 32256; which = 4; }
        else                { src = xp; local = g - 33792; which = 5; }
        float v = LD(src, local, dts[which]);
        int out = g;
        if (which == 3) v = -__expf(v) * 1.44269504f;   // A2 = -exp(A_log)*log2e
        if (which == 0) out = (local % 3) * DINNER + local / 3;  // conv planes
        pf[out] = v;
    } else if (blk < 1860) {
        if (t == 0) dts[0] = detect_dtype(x);
        __syncthreads();
        const int dt = dts[0];
        size_t i = ((size_t)(blk - 324) * 256 + t) * 8;
        ushort4 o0, o1;
        if (dt == DT_F32) {
            float4 a = *(const float4*)((const float*)x + i);
            float4 b = *(const float4*)((const float*)x + i + 4);
            o0.x = f2bf(a.x); o0.y = f2bf(a.y); o0.z = f2bf(a.z); o0.w = f2bf(a.w);
            o1.x = f2bf(b.x); o1.y = f2bf(b.y); o1.z = f2bf(b.z); o1.w = f2bf(b.w);
        } else if (dt == DT_BF16) {
            o0 = *(const ushort4*)((const unsigned short*)x + i);
            o1 = *(const ushort4*)((const unsigned short*)x + i + 4);
        } else {
            o0 = (ushort4){0,0,0,0}; o1 = (ushort4){0,0,0,0};
        }
        *(ushort4*)&xb[i] = o0;
        *(ushort4*)&xb[i + 4] = o1;
    } else if (blk < 3300) {
        const void* src; unsigned short* dst; int R, C, tx_n, idx;
        if (blk < 2436)      { src = in_w;  dst = inT;  R = 768;  C = 3072; tx_n = 48; idx = blk - 1860; }
        else if (blk < 3012) { src = dt_w;  dst = dtT;  R = 1536; C = 1536; tx_n = 24; idx = blk - 2436; }
        else                 { src = out_w; dst = outT; R = 1536; C = 768;  tx_n = 12; idx = blk - 3012; }
        if (t == 0) dts[0] = detect_dtype(src);
        __syncthreads();
        const int dt = dts[0];
        const int tx = t & 15, ty = t >> 4;          // 16 x 16 threads
        const int bx = (idx % tx_n) * 64, by = (idx / tx_n) * 64;
        #pragma unroll
        for (int i = 0; i < 4; ++i) {
            int rl = ty + i * 16;
            size_t soff = (size_t)(by + rl) * C + bx + tx * 4;
            ushort4 hv;
            if (dt == DT_F32) {
                float4 v = *(const float4*)((const float*)src + soff);
                hv.x = f2bf(v.x); hv.y = f2bf(v.y); hv.z = f2bf(v.z); hv.w = f2bf(v.w);
            } else if (dt == DT_BF16) {
                hv = *(const ushort4*)((const unsigned short*)src + soff);
            } else {
                hv = (ushort4){0,0,0,0};
            }
            *(ushort4*)&tile[rl][tx * 4] = hv;
        }
        __syncthreads();
        #pragma unroll
        for (int i = 0; i < 4; ++i) {
            int cl = ty + i * 16;
            int m0 = tx * 4;
            ushort4 o;
            o.x = tile[m0 + 0][cl]; o.y = tile[m0 + 1][cl];
            o.z = tile[m0 + 2][cl]; o.w = tile[m0 + 3][cl];
            *(ushort4*)&dst[(size_t)(bx + cl) * R + by + m0] = o;
        }
    } else {
        // xproj transpose -> bf16 xpT[32][1536]
        if (t == 0) dts[0] = detect_dtype(xp);
        __syncthreads();
        const int dt = dts[0];
        int r = (blk - 3300) * 256 + t;              // 0..1535
        #pragma unroll 4
        for (int c = 0; c < 32; ++c) {
            float v = LD(xp, (size_t)r * 32 + c, dt);
            xpT[(size_t)c * DINNER + r] = f2bf(v);
        }
    }
}

// ---- MFMA GEMM: C = A[M][K] @ Bt[N][K]^T, 128x64 tile, BK=64, dbuf async ----
// Granule rotation: slot (row,g) holds k-granule (g - (row>>1)) & 3 per panel.
// EPI 2: f32  C0 = v (final output)
// EPI 3: col < N/2 -> bf16 C0 = v ; else bf16 C1 = silu(v)
// EPI 4: fused dt+xproj. Bt covers rows [0,1536) (dtT), Bt2 rows [1536,1568)
//        (xpT); grid y=25 (cols 0..1599, >=1568 discarded, B rows clamped).
//        col<1536: bf16 C0 = softplus(v + biasf[col]) (stride 1536);
//        1536<=col<1568: f32 C1[row*32 + col-1536] = v (BC).
template<int EPI>
__global__ __launch_bounds__(256) void gemm_kernel(
    const unsigned short* __restrict__ A, const unsigned short* __restrict__ Bt,
    const unsigned short* __restrict__ Bt2,
    void* __restrict__ C0, void* __restrict__ C1, const float* __restrict__ biasf,
    int M, int N, int K)
{
    __shared__ __align__(16) unsigned short As[2][2][128 * 32];   // 32 KB
    __shared__ __align__(16) unsigned short Bs[2][2][64 * 32];    // 16 KB
    const int t    = threadIdx.x;
    const int m0   = blockIdx.x * 128;
    const int n0   = blockIdx.y * 64;
    const int w    = t >> 6;
    const int lane = t & 63;
    const int wm   = (w >> 1) * 64, wn = (w & 1) * 32;
    const int lm   = lane & 15, quad = lane >> 4;
    const int srow = lane >> 2;          // staging: row within 16-row group
    const int sg   = lane & 3;           // staging: granule slot

    f32x4 acc[4][2] = {};

    auto stage = [&](int k0, int q) {
        #pragma unroll
        for (int ph = 0; ph < 2; ++ph) {
            #pragma unroll
            for (int h = 0; h < 2; ++h) {
                int row = w * 32 + h * 16 + srow;
                int kg  = (sg - (row >> 1)) & 3;
                async_cp16((glob_us*)&A[(size_t)(m0 + row) * K + k0 + ph * 32 + kg * 8],
                           (lds_us*)&As[q][ph][(w * 32 + h * 16) * 32]);
            }
            int brow = w * 16 + srow;
            int bkg  = (sg - (brow >> 1)) & 3;
            const unsigned short* bsrc;
            if (EPI == 4) {
                int gr = n0 + brow;
                bsrc = (gr < 1536) ? &Bt[(size_t)gr * K]
                                   : &Bt2[(size_t)(((gr < 1567) ? gr : 1567) - 1536) * K];
            } else {
                bsrc = &Bt[(size_t)(n0 + brow) * K];
            }
            async_cp16((glob_us*)&bsrc[k0 + ph * 32 + bkg * 8],
                       (lds_us*)&Bs[q][ph][(w * 16) * 32]);
        }
    };

    // prologue: stage tile 0 into buffer 0
    stage(0, 0);

    int p = 0;
    for (int k0 = 0; k0 < K; k0 += 64) {
        __syncthreads();                       // drains stage(k0) into buf p
        if (k0 + 64 < K) stage(k0 + 64, p ^ 1);  // overlaps with 16 MFMAs below
        #pragma unroll
        for (int ph = 0; ph < 2; ++ph) {
            bf16x8 af[4], bfr[2];
            #pragma unroll
            for (int i = 0; i < 4; ++i) {
                int row = wm + i * 16 + lm;
                int g   = (quad + (row >> 1)) & 3;
                af[i] = *(const bf16x8*)&As[p][ph][row * 32 + g * 8];
            }
            #pragma unroll
            for (int j = 0; j < 2; ++j) {
                int row = wn + j * 16 + lm;
                int g   = (quad + (row >> 1)) & 3;
                bfr[j] = *(const bf16x8*)&Bs[p][ph][row * 32 + g * 8];
            }
            #pragma unroll
            for (int i = 0; i < 4; ++i)
                #pragma unroll
                for (int j = 0; j < 2; ++j)
                    acc[i][j] = __builtin_amdgcn_mfma_f32_16x16x32_bf16(af[i], bfr[j], acc[i][j], 0, 0, 0);
        }
        p ^= 1;
    }

    const int half = N >> 1;
    #pragma unroll
    for (int i = 0; i < 4; ++i) {
        #pragma unroll
        for (int j = 0; j < 2; ++j) {
            int col = n0 + wn + j * 16 + lm;
            #pragma unroll
            for (int r = 0; r < 4; ++r) {
                int row = m0 + wm + i * 16 + quad * 4 + r;
                float v = acc[i][j][r];
                if (EPI == 2) {
                    ((float*)C0)[(size_t)row * N + col] = v;
                } else if (EPI == 3) {
                    if (col < half) {
                        ((unsigned short*)C0)[(size_t)row * half + col] = f2bf(v);
                    } else {
                        float s = v / (1.f + __expf(-v));
                        ((unsigned short*)C1)[(size_t)row * half + col - half] = f2bf(s);
                    }
                } else {   // EPI 4
                    if (col < 1536) {
                        v += biasf[col];
                        float sp = (v > 20.f) ? v : log1pf(__expf(v));
                        ((unsigned short*)C0)[(size_t)row * 1536 + col] = f2bf(sp);
                    } else if (col < 1568) {
                        ((float*)C1)[(size_t)row * 32 + (col - 1536)] = v;
                    }
                }
            }
        }
    }
}

// ---- depthwise conv3 + bias + SiLU, 8 d/thread, plane weights ----
__global__ __launch_bounds__(256) void conv_silu_kernel(
    const unsigned short* __restrict__ xcpre, const float* __restrict__ cwf,
    const float* __restrict__ cbf, unsigned short* __restrict__ xcb)
{
    const float* cw0 = cwf;
    const float* cw1 = cwf + DINNER;
    const float* cw2 = cwf + 2 * DINNER;
    size_t idx = ((size_t)blockIdx.x * 256 + threadIdx.x) * 8;
    int d8  = (int)(idx % DINNER);
    int row = (int)(idx / DINNER);
    int l   = row % SEQL;
    size_t base = (size_t)row * DINNER + d8;
    uint4 zero = {0, 0, 0, 0};
    uint4 xm = (l > 0)        ? *(const uint4*)&xcpre[base - DINNER] : zero;
    uint4 x0 = *(const uint4*)&xcpre[base];
    uint4 xp = (l < SEQL - 1) ? *(const uint4*)&xcpre[base + DINNER] : zero;
    float4 c0a = *(const float4*)&cw0[d8], c0b = *(const float4*)&cw0[d8 + 4];
    float4 c1a = *(const float4*)&cw1[d8], c1b = *(const float4*)&cw1[d8 + 4];
    float4 c2a = *(const float4*)&cw2[d8], c2b = *(const float4*)&cw2[d8 + 4];
    float4 cba = *(const float4*)&cbf[d8], cbb = *(const float4*)&cbf[d8 + 4];
    const unsigned* mw = (const unsigned*)&xm;
    const unsigned* zw = (const unsigned*)&x0;
    const unsigned* pw = (const unsigned*)&xp;
    float w0[8] = {c0a.x, c0a.y, c0a.z, c0a.w, c0b.x, c0b.y, c0b.z, c0b.w};
    float w1[8] = {c1a.x, c1a.y, c1a.z, c1a.w, c1b.x, c1b.y, c1b.z, c1b.w};
    float w2[8] = {c2a.x, c2a.y, c2a.z, c2a.w, c2b.x, c2b.y, c2b.z, c2b.w};
    float bb[8] = {cba.x, cba.y, cba.z, cba.w, cbb.x, cbb.y, cbb.z, cbb.w};
    unsigned short out[8];
    #pragma unroll
    for (int k = 0; k < 8; ++k) {
        unsigned wm_ = mw[k >> 1], wz = zw[k >> 1], wp = pw[k >> 1];
        float a = (k & 1) ? bfhi(wm_) : bflo(wm_);
        float c = (k & 1) ? bfhi(wz)  : bflo(wz);
        float e = (k & 1) ? bfhi(wp)  : bflo(wp);
        float acc = bb[k] + a * w0[k] + c * w1[k] + e * w2[k];
        float s = acc / (1.f + __expf(-acc));
        out[k] = f2bf(s);
    }
    *(uint4*)&xcb[base] = *(uint4*)out;
}

// ====== chunked scan, q-split x 4-d-per-thread, register ping-pong ======
// Thread: q = t&3 owns states [4q,4q+4) of d..d+3 (d = 4*(dg*64 + t>>2)).
// Packed 8B dv/xv loads (4 bf16), one Bv/Cv per 4 d, DPP quad reduce.
struct Grp4A { uint2 dv[4], xv[4]; f32x4 Bv[4]; };
struct Grp4C { uint2 dv[4], xv[4]; f32x4 Bv[4], Cv[4]; };

__device__ __forceinline__ void ldA4(Grp4A& gp, const unsigned short* pd,
    const unsigned short* px, const float* pbc, int l) {
    #pragma unroll
    for (int j = 0; j < 4; ++j) {
        size_t o = (size_t)(l + j) * DINNER;
        gp.dv[j] = *(const uint2*)&pd[o];
        gp.xv[j] = *(const uint2*)&px[o];
        gp.Bv[j] = *(const f32x4*)&pbc[(size_t)(l + j) * 32];
    }
}
__device__ __forceinline__ void ldC4(Grp4C& gp, const unsigned short* pd,
    const unsigned short* px, const float* pbc, int l) {
    #pragma unroll
    for (int j = 0; j < 4; ++j) {
        size_t o = (size_t)(l + j) * DINNER;
        gp.dv[j] = *(const uint2*)&pd[o];
        gp.xv[j] = *(const uint2*)&px[o];
        gp.Bv[j] = *(const f32x4*)&pbc[(size_t)(l + j) * 32];
        gp.Cv[j] = *(const f32x4*)&pbc[(size_t)(l + j) * 32 + 16];
    }
}

__global__ __launch_bounds__(256) void scan_phase_a(
    const unsigned short* __restrict__ dlt, const unsigned short* __restrict__ xcb,
    const float* __restrict__ BC, const float* __restrict__ A_log_f,
    unsigned short* __restrict__ P, float* __restrict__ S)
{
    const int t   = threadIdx.x;
    const int q   = t & 3;
    const int dpl = t >> 2;                       // 0..63
    const int bid = blockIdx.x;
    const int dg  = bid % 6;
    const int cc  = (bid / 6) % NCHUNK;
    const int b   = bid / (6 * NCHUNK);
    const int d   = (dg * 64 + dpl) * 4;
    f32x4 A2[4];
    #pragma unroll
    for (int dd = 0; dd < 4; ++dd)
        A2[dd] = *(const f32x4*)&A_log_f[(d + dd) * 16 + q * 4];
    f32x4 h[4] = {};
    float sdv[4] = {0.f, 0.f, 0.f, 0.f};
    const int row0 = b * SEQL + cc * CHLEN;
    const unsigned short* pd = dlt + (size_t)row0 * DINNER + d;
    const unsigned short* px = xcb + (size_t)row0 * DINNER + d;
    const float* pbc = BC + (size_t)row0 * 32 + q * 4;

    auto stepA = [&](const Grp4A& gp) {
        #pragma unroll
        for (int j = 0; j < 4; ++j) {
            float dvv[4] = {bflo(gp.dv[j].x), bfhi(gp.dv[j].x), bflo(gp.dv[j].y), bfhi(gp.dv[j].y)};
            float xvv[4] = {bflo(gp.xv[j].x), bfhi(gp.xv[j].x), bflo(gp.xv[j].y), bfhi(gp.xv[j].y)};
            f32x4 Bv = gp.Bv[j];
            #pragma unroll
            for (int dd = 0; dd < 4; ++dd) {
                sdv[dd] += dvv[dd];
                f32x4 e;
                e[0] = __builtin_amdgcn_exp2f(dvv[dd] * A2[dd][0]);
                e[1] = __builtin_amdgcn_exp2f(dvv[dd] * A2[dd][1]);
                e[2] = __builtin_amdgcn_exp2f(dvv[dd] * A2[dd][2]);
                e[3] = __builtin_amdgcn_exp2f(dvv[dd] * A2[dd][3]);
                h[dd] = e * h[dd] + (dvv[dd] * xvv[dd]) * Bv;
            }
        }
    };

    Grp4A ga, gb;
    ldA4(ga, pd, px, pbc, 0);
    for (int l0 = 0; l0 < CHLEN; l0 += 8) {
        ldA4(gb, pd, px, pbc, l0 + 4);
        stepA(ga);
        if (l0 + 8 < CHLEN) ldA4(ga, pd, px, pbc, l0 + 8);
        stepA(gb);
    }

    size_t idx = (((size_t)(b * NCHUNK + cc)) * DINNER + d) * 16 + q * 4;
    #pragma unroll
    for (int dd = 0; dd < 4; ++dd) {
        *(f32x4*)&S[idx + dd * 16] = h[dd];
        ushort4 pq;
        pq.x = f2bf(__builtin_amdgcn_exp2f(sdv[dd] * A2[dd][0]));
        pq.y = f2bf(__builtin_amdgcn_exp2f(sdv[dd] * A2[dd][1]));
        pq.z = f2bf(__builtin_amdgcn_exp2f(sdv[dd] * A2[dd][2]));
        pq.w = f2bf(__builtin_amdgcn_exp2f(sdv[dd] * A2[dd][3]));
        *(ushort4*)&P[idx + dd * 16] = pq;
    }
}

__global__ __launch_bounds__(256) void scan_combine(
    const unsigned short* __restrict__ P, float* __restrict__ S)
{
    int t = blockIdx.x * 256 + threadIdx.x;            // < 2*1536*16
    int b = t / (DINNER * NSTATE);
    int dn = t % (DINNER * NSTATE);
    const size_t stride = (size_t)(DINNER * NSTATE);
    size_t idx = (size_t)b * NCHUNK * stride + dn;
    float Pv = bf2f(P[idx]);
    float Sv = S[idx];
    float H = 0.f;
    for (int c = 0; c < NCHUNK; ++c) {
        float Pn = 0.f, Sn = 0.f;
        if (c + 1 < NCHUNK) {                  // prefetch next chunk
            Pn = bf2f(P[idx + stride]);
            Sn = S[idx + stride];
        }
        S[idx] = H;                 // Hin for chunk c
        H = Pv * H + Sv;
        Pv = Pn; Sv = Sn;
        idx += stride;
    }
}

__global__ __launch_bounds__(256) void scan_phase_c(
    const unsigned short* __restrict__ dlt, const unsigned short* __restrict__ xcb,
    const float* __restrict__ BC, const unsigned short* __restrict__ zg,
    const float* __restrict__ A_log_f, const float* __restrict__ D_f,
    const float* __restrict__ Hin, unsigned short* __restrict__ yg)
{
    const int t   = threadIdx.x;
    const int q   = t & 3;
    const int dpl = t >> 2;
    const int bid = blockIdx.x;
    const int dg  = bid % 6;
    const int cc  = (bid / 6) % NCHUNK;
    const int b   = bid / (6 * NCHUNK);
    const int d   = (dg * 64 + dpl) * 4;
    f32x4 A2[4];
    float Dd[4];
    #pragma unroll
    for (int dd = 0; dd < 4; ++dd) {
        A2[dd] = *(const f32x4*)&A_log_f[(d + dd) * 16 + q * 4];
        Dd[dd] = D_f[d + dd];
    }
    size_t hidx = (((size_t)(b * NCHUNK + cc)) * DINNER + d) * 16 + q * 4;
    f32x4 h[4];
    #pragma unroll
    for (int dd = 0; dd < 4; ++dd) h[dd] = *(const f32x4*)&Hin[hidx + dd * 16];
    const int row0 = b * SEQL + cc * CHLEN;
    const unsigned short* pd = dlt + (size_t)row0 * DINNER + d;
    const unsigned short* px = xcb + (size_t)row0 * DINNER + d;
    const unsigned short* pz = zg  + (size_t)row0 * DINNER + d;
    unsigned short* py = yg + (size_t)row0 * DINNER + d;
    const float* pbc = BC + (size_t)row0 * 32 + q * 4;

    auto stepC = [&](const Grp4C& gp, int l) {
        #pragma unroll
        for (int j = 0; j < 4; ++j) {
            float dvv[4] = {bflo(gp.dv[j].x), bfhi(gp.dv[j].x), bflo(gp.dv[j].y), bfhi(gp.dv[j].y)};
            float xvv[4] = {bflo(gp.xv[j].x), bfhi(gp.xv[j].x), bflo(gp.xv[j].y), bfhi(gp.xv[j].y)};
            f32x4 Bv = gp.Bv[j], Cv = gp.Cv[j];
            float y[4];
            #pragma unroll
            for (int dd = 0; dd < 4; ++dd) {
                f32x4 e;
                e[0] = __builtin_amdgcn_exp2f(dvv[dd] * A2[dd][0]);
                e[1] = __builtin_amdgcn_exp2f(dvv[dd] * A2[dd][1]);
                e[2] = __builtin_amdgcn_exp2f(dvv[dd] * A2[dd][2]);
                e[3] = __builtin_amdgcn_exp2f(dvv[dd] * A2[dd][3]);
                h[dd] = e * h[dd] + (dvv[dd] * xvv[dd]) * Bv;
                f32x4 yv = h[dd] * Cv;
                y[dd] = quad_reduce(yv[0] + yv[1] + yv[2] + yv[3]);
            }
            if (j == q) {                      // rotated store: lane q owns step j
                uint2 zp = *(const uint2*)&pz[(size_t)(l + j) * DINNER];
                float zv[4] = {bflo(zp.x), bfhi(zp.x), bflo(zp.y), bfhi(zp.y)};
                ushort4 o;
                o.x = f2bf((y[0] + Dd[0] * xvv[0]) * zv[0]);
                o.y = f2bf((y[1] + Dd[1] * xvv[1]) * zv[1]);
                o.z = f2bf((y[2] + Dd[2] * xvv[2]) * zv[2]);
                o.w = f2bf((y[3] + Dd[3] * xvv[3]) * zv[3]);
                *(ushort4*)&py[(size_t)(l + j) * DINNER] = o;
            }
        }
    };

    Grp4C ga, gb;
    ldC4(ga, pd, px, pbc, 0);
    for (int l0 = 0; l0 < CHLEN; l0 += 8) {
        ldC4(gb, pd, px, pbc, l0 + 4);
        stepC(ga, l0);
        if (l0 + 8 < CHLEN) ldC4(ga, pd, px, pbc, l0 + 8);
        stepC(gb, l0 + 4);
    }
}

__global__ void guard_kernel(float* out, int code)
{
    if (threadIdx.x == 0 && blockIdx.x == 0 && code) out[0] = (float)code;
}

extern "C" void kernel_launch(void* const* d_in, const int* in_sizes, int n_in,
                              void* d_out, int out_size, void* d_ws, size_t ws_size,
                              hipStream_t stream) {
    static const int EXPECTED[10] = {3145728, 2359296, 4608, 1536, 49152,
                                     2359296, 1536, 24576, 1536, 1179648};
    bool ok = (n_in == 10);
    if (ok) for (int i = 0; i < 10; ++i) ok = ok && (in_sizes[i] == EXPECTED[i]);
    int code = 0;
    if (!ok) code = 2000;
    else if (ws_size < 67895296ULL) code = 3000;
    if (code) { guard_kernel<<<1, 64, 0, stream>>>((float*)d_out, code); return; }

    const void* x       = d_in[0];
    const void* in_w    = d_in[1];
    const void* conv_w  = d_in[2];
    const void* conv_b  = d_in[3];
    const void* xproj_w = d_in[4];
    const void* dt_w    = d_in[5];
    const void* dt_b    = d_in[6];
    const void* A_log   = d_in[7];
    const void* Dvec    = d_in[8];
    const void* out_w   = d_in[9];

    char* ws = (char*)d_ws;
    float* conv_w_f = (float*)(ws + 0);        // 3 planes x 1536 f32 (18432 B)
    float* conv_b_f = (float*)(ws + 18432);    // 1536
    float* dt_b_f   = (float*)(ws + 24576);    // 1536
    float* A_log_f  = (float*)(ws + 30720);    // 24576 (holds A2 = -exp(A_log)*log2e)
    float* D_f      = (float*)(ws + 129024);   // 1536
    // legacy f32 xproj copy still written by prep at [135168, 331776)
    unsigned short* xpT   = (unsigned short*)(ws + 331776);    // [32][1536] bf16, ends 430080
    unsigned short* xb    = (unsigned short*)(ws + 524288);    // [4096][768]  (dead after gemm1)
    unsigned short* inT   = (unsigned short*)(ws + 6815744);   // [3072][768]  (dead after gemm1)
    unsigned short* yg    = (unsigned short*)(ws + 524288);    // [4096][1536] alias xb+inT
    unsigned short* dtT   = (unsigned short*)(ws + 13107200);  // [1536][1536]
    unsigned short* outT  = (unsigned short*)(ws + 17825792);  // [768][1536]
    unsigned short* xcpre = (unsigned short*)(ws + 20185088);  // [4096][1536] (dead after conv)
    unsigned short* dlt   = xcpre;                             // alias (gemm2 out)
    float*          BC    = (float*)(ws + 32768000);           // [4096][32]
    unsigned short* zg    = (unsigned short*)(ws + 33292288);  // [4096][1536] silu(z)
    unsigned short* xcb   = (unsigned short*)(ws + 45875200);  // [4096][1536]
    float*          scanS = (float*)(ws + 58458112);           // [2][32][1536][16] f32 6.29MB
    unsigned short* scanP = (unsigned short*)(ws + 64749568);  // same shape bf16   3.15MB

    prep_kernel<<<3306, 256, 0, stream>>>(x, in_w, conv_w, conv_b, xproj_w, dt_w,
                                          dt_b, A_log, Dvec, out_w,
                                          xb, inT, dtT, outT, xpT, (float*)ws);

    gemm_kernel<3><<<dim3(32, 48), 256, 0, stream>>>(xb, inT, nullptr, (void*)xcpre,
                                                     (void*)zg, nullptr, 4096, 3072, 768);
    conv_silu_kernel<<<(4096 * DINNER / 8) / 256, 256, 0, stream>>>(xcpre, conv_w_f, conv_b_f, xcb);
    gemm_kernel<4><<<dim3(32, 25), 256, 0, stream>>>(xcb, dtT, xpT, (void*)dlt,
                                                     (void*)BC, dt_b_f, 4096, 1536, 1536);
    scan_phase_a<<<384, 256, 0, stream>>>(dlt, xcb, BC, A_log_f, scanP, scanS);
    scan_combine<<<192, 256, 0, stream>>>(scanP, scanS);
    scan_phase_c<<<384, 256, 0, stream>>>(dlt, xcb, BC, zg, A_log_f, D_f, scanS, yg);
    gemm_kernel<2><<<dim3(32, 12), 256, 0, stream>>>(yg, outT, nullptr, d_out,
                                                     nullptr, nullptr, 4096, 768, 1536);
}

// Round 12
// 299.678 us; speedup vs baseline: 1.0686x; 1.0686x over previous
//
#include <hip/hip_runtime.h>
#include <cmath>

// SimplifiedSSM: B=2, L=2048, d_model=768, d_state=16, d_inner=1536
// ROUND 26: R25 fusion kept but fixed: (1) fused dt+xproj GEMM moved to the
// R14-proven BK=32 / 24KB-LDS structure -> 6 blocks/CU = 1536 slots, so the
// 800-block grid is fully co-resident (R25's 48KB/3-per-CU gave exactly 768
// slots -> 32-block straggler round = +11us). B-source (dtT rows <1536 /
// xpT rows >=1536) hoisted to one loop-invariant per-thread base pointer.
// (2) scans reverted to R23's proven 2-d packing (R25's 4-d was +2.5us).
// in/out-proj GEMMs stay BK=64; prep/conv/combine unchanged.
#define DMODEL 768
#define DINNER 1536
#define NSTATE 16
#define SEQL   2048
#define NCHUNK 32
#define CHLEN  64      // SEQL / NCHUNK

#define DT_F32  0
#define DT_BF16 1
#define DT_ZERO 2

typedef __bf16 bf16x8 __attribute__((ext_vector_type(8)));
typedef float  f32x4  __attribute__((ext_vector_type(4)));

typedef __attribute__((address_space(3))) unsigned short lds_us;
typedef const __attribute__((address_space(1))) unsigned short glob_us;

__device__ __forceinline__ void async_cp16(glob_us* g, lds_us* l) {
    __builtin_amdgcn_global_load_lds((const __attribute__((address_space(1))) void*)g,
                                     (__attribute__((address_space(3))) void*)l, 16, 0, 0);
}

__device__ __forceinline__ float bf2f(unsigned short h) {
    union { unsigned u; float f; } v; v.u = ((unsigned)h) << 16; return v.f;
}
__device__ __forceinline__ float bflo(unsigned p) {
    union { unsigned u; float f; } v; v.u = p << 16; return v.f;
}
__device__ __forceinline__ float bfhi(unsigned p) {
    union { unsigned u; float f; } v; v.u = p & 0xFFFF0000u; return v.f;
}
__device__ __forceinline__ unsigned short f2bf(float f) {
    union { float f; unsigned u; } v; v.f = f;
    unsigned r = (v.u + 0x7FFFu + ((v.u >> 16) & 1u)) >> 16;
    return (unsigned short)r;
}
// butterfly sum over 4-lane quads via DPP (all lanes get the total)
__device__ __forceinline__ float quad_reduce(float y) {
    int yi = __float_as_int(y);
    y += __int_as_float(__builtin_amdgcn_mov_dpp(yi, 0xB1, 0xF, 0xF, true)); // quad_perm [1,0,3,2]
    yi = __float_as_int(y);
    y += __int_as_float(__builtin_amdgcn_mov_dpp(yi, 0x4E, 0xF, 0xF, true)); // quad_perm [2,3,0,1]
    return y;
}
__device__ int detect_dtype(const void* p) {
    const unsigned* u = (const unsigned*)p;
    int nzlo = 0, band = 0, anynz = 0;
    for (int i = 0; i < 64; ++i) {
        unsigned w = u[i];
        anynz |= (w != 0);
        unsigned lo = w & 0xFFFFu;
        if (lo) {
            ++nzlo;
            unsigned e8 = (lo >> 7) & 0xFF;
            if (e8 >= 0x60 && e8 <= 0x8E) ++band;
        }
    }
    if (nzlo >= 8) return (band * 2 > nzlo) ? DT_BF16 : DT_F32;
    return anynz ? DT_F32 : DT_ZERO;
}
__device__ __forceinline__ float LD(const void* p, size_t i, int dt) {
    if (dt == DT_BF16) return bf2f(((const unsigned short*)p)[i]);
    if (dt == DT_F32)  return ((const float*)p)[i];
    return 0.f;
}

// ---- fused prep: params->f32 (A_log -> A2, conv_w -> 3 planes) | x->bf16 |
//      3 weight transposes | xproj -> bf16 transpose [32][1536] ----
// blocks: [0,324) params, [324,1860) x (8 elem/thread),
//         [1860,2436) in_w, [2436,3012) dt_w, [3012,3300) out_w (64x64 tiles),
//         [3300,3306) xpT
__global__ __launch_bounds__(256) void prep_kernel(
    const void* __restrict__ x, const void* __restrict__ in_w,
    const void* __restrict__ cw, const void* __restrict__ cb,
    const void* __restrict__ xp, const void* __restrict__ dt_w,
    const void* __restrict__ db, const void* __restrict__ Al,
    const void* __restrict__ Dv, const void* __restrict__ out_w,
    unsigned short* __restrict__ xb, unsigned short* __restrict__ inT,
    unsigned short* __restrict__ dtT, unsigned short* __restrict__ outT,
    unsigned short* __restrict__ xpT, float* __restrict__ pf)
{
    __shared__ unsigned short tile[64][68];
    __shared__ int dts[6];
    const int blk = blockIdx.x;
    const int t   = threadIdx.x;

    if (blk < 324) {
        if (t == 0) {
            dts[0] = detect_dtype(cw); dts[1] = detect_dtype(cb);
            dts[2] = detect_dtype(db); dts[3] = detect_dtype(Al);
            dts[4] = detect_dtype(Dv); dts[5] = detect_dtype(xp);
        }
        __syncthreads();
        int g = blk * 256 + t;
        if (g >= 82944) return;
        const void* src; int local; int which;
        if      (g <  4608) { src = cw; local = g;         which = 0; }
        else if (g <  6144) { src = cb; local = g - 4608;  which = 1; }
        else if (g <  7680) { src = db; local = g - 6144;  which = 2; }
        else if (g < 32256) { src = Al; local = g - 7680;  which = 3; }
        else if (g < 33792) { src = Dv; local = g - 32256; which = 4; }
        else                { src = xp; local = g - 33792; which = 5; }
        float v = LD(src, local, dts[which]);
        int out = g;
        if (which == 3) v = -__expf(v) * 1.44269504f;   // A2 = -exp(A_log)*log2e
        if (which == 0) out = (local % 3) * DINNER + local / 3;  // conv planes
        pf[out] = v;
    } else if (blk < 1860) {
        if (t == 0) dts[0] = detect_dtype(x);
        __syncthreads();
        const int dt = dts[0];
        size_t i = ((size_t)(blk - 324) * 256 + t) * 8;
        ushort4 o0, o1;
        if (dt == DT_F32) {
            float4 a = *(const float4*)((const float*)x + i);
            float4 b = *(const float4*)((const float*)x + i + 4);
            o0.x = f2bf(a.x); o0.y = f2bf(a.y); o0.z = f2bf(a.z); o0.w = f2bf(a.w);
            o1.x = f2bf(b.x); o1.y = f2bf(b.y); o1.z = f2bf(b.z); o1.w = f2bf(b.w);
        } else if (dt == DT_BF16) {
            o0 = *(const ushort4*)((const unsigned short*)x + i);
            o1 = *(const ushort4*)((const unsigned short*)x + i + 4);
        } else {
            o0 = (ushort4){0,0,0,0}; o1 = (ushort4){0,0,0,0};
        }
        *(ushort4*)&xb[i] = o0;
        *(ushort4*)&xb[i + 4] = o1;
    } else if (blk < 3300) {
        const void* src; unsigned short* dst; int R, C, tx_n, idx;
        if (blk < 2436)      { src = in_w;  dst = inT;  R = 768;  C = 3072; tx_n = 48; idx = blk - 1860; }
        else if (blk < 3012) { src = dt_w;  dst = dtT;  R = 1536; C = 1536; tx_n = 24; idx = blk - 2436; }
        else                 { src = out_w; dst = outT; R = 1536; C = 768;  tx_n = 12; idx = blk - 3012; }
        if (t == 0) dts[0] = detect_dtype(src);
        __syncthreads();
        const int dt = dts[0];
        const int tx = t & 15, ty = t >> 4;          // 16 x 16 threads
        const int bx = (idx % tx_n) * 64, by = (idx / tx_n) * 64;
        #pragma unroll
        for (int i = 0; i < 4; ++i) {
            int rl = ty + i * 16;
            size_t soff = (size_t)(by + rl) * C + bx + tx * 4;
            ushort4 hv;
            if (dt == DT_F32) {
                float4 v = *(const float4*)((const float*)src + soff);
                hv.x = f2bf(v.x); hv.y = f2bf(v.y); hv.z = f2bf(v.z); hv.w = f2bf(v.w);
            } else if (dt == DT_BF16) {
                hv = *(const ushort4*)((const unsigned short*)src + soff);
            } else {
                hv = (ushort4){0,0,0,0};
            }
            *(ushort4*)&tile[rl][tx * 4] = hv;
        }
        __syncthreads();
        #pragma unroll
        for (int i = 0; i < 4; ++i) {
            int cl = ty + i * 16;
            int m0 = tx * 4;
            ushort4 o;
            o.x = tile[m0 + 0][cl]; o.y = tile[m0 + 1][cl];
            o.z = tile[m0 + 2][cl]; o.w = tile[m0 + 3][cl];
            *(ushort4*)&dst[(size_t)(bx + cl) * R + by + m0] = o;
        }
    } else {
        // xproj transpose -> bf16 xpT[32][1536]
        if (t == 0) dts[0] = detect_dtype(xp);
        __syncthreads();
        const int dt = dts[0];
        int r = (blk - 3300) * 256 + t;              // 0..1535
        #pragma unroll 4
        for (int c = 0; c < 32; ++c) {
            float v = LD(xp, (size_t)r * 32 + c, dt);
            xpT[(size_t)c * DINNER + r] = f2bf(v);
        }
    }
}

// ---- MFMA GEMM: C = A[M][K] @ Bt[N][K]^T, 128x64 tile, BK=64, dbuf async ----
// (R20 structure, frozen.) Granule rotation: slot (row,g) holds k-granule
// (g - (row>>1)) & 3 within its 32-K panel.
// EPI 2: f32  C0 = v (final output)
// EPI 3: col < N/2 -> bf16 C0 = v ; else bf16 C1 = silu(v)
template<int EPI>
__global__ __launch_bounds__(256) void gemm_kernel(
    const unsigned short* __restrict__ A, const unsigned short* __restrict__ Bt,
    void* __restrict__ C0, void* __restrict__ C1, const float* __restrict__ biasf,
    int M, int N, int K)
{
    __shared__ __align__(16) unsigned short As[2][2][128 * 32];   // 32 KB
    __shared__ __align__(16) unsigned short Bs[2][2][64 * 32];    // 16 KB
    const int t    = threadIdx.x;
    const int m0   = blockIdx.x * 128;
    const int n0   = blockIdx.y * 64;
    const int w    = t >> 6;
    const int lane = t & 63;
    const int wm   = (w >> 1) * 64, wn = (w & 1) * 32;
    const int lm   = lane & 15, quad = lane >> 4;
    const int srow = lane >> 2;          // staging: row within 16-row group
    const int sg   = lane & 3;           // staging: granule slot

    f32x4 acc[4][2] = {};

    auto stage = [&](int k0, int q) {
        #pragma unroll
        for (int ph = 0; ph < 2; ++ph) {
            #pragma unroll
            for (int h = 0; h < 2; ++h) {
                int row = w * 32 + h * 16 + srow;
                int kg  = (sg - (row >> 1)) & 3;
                async_cp16((glob_us*)&A[(size_t)(m0 + row) * K + k0 + ph * 32 + kg * 8],
                           (lds_us*)&As[q][ph][(w * 32 + h * 16) * 32]);
            }
            int brow = w * 16 + srow;
            int bkg  = (sg - (brow >> 1)) & 3;
            async_cp16((glob_us*)&Bt[(size_t)(n0 + brow) * K + k0 + ph * 32 + bkg * 8],
                       (lds_us*)&Bs[q][ph][(w * 16) * 32]);
        }
    };

    // prologue: stage tile 0 into buffer 0
    stage(0, 0);

    int p = 0;
    for (int k0 = 0; k0 < K; k0 += 64) {
        __syncthreads();                       // drains stage(k0) into buf p
        if (k0 + 64 < K) stage(k0 + 64, p ^ 1);  // overlaps with 16 MFMAs below
        #pragma unroll
        for (int ph = 0; ph < 2; ++ph) {
            bf16x8 af[4], bfr[2];
            #pragma unroll
            for (int i = 0; i < 4; ++i) {
                int row = wm + i * 16 + lm;
                int g   = (quad + (row >> 1)) & 3;
                af[i] = *(const bf16x8*)&As[p][ph][row * 32 + g * 8];
            }
            #pragma unroll
            for (int j = 0; j < 2; ++j) {
                int row = wn + j * 16 + lm;
                int g   = (quad + (row >> 1)) & 3;
                bfr[j] = *(const bf16x8*)&Bs[p][ph][row * 32 + g * 8];
            }
            #pragma unroll
            for (int i = 0; i < 4; ++i)
                #pragma unroll
                for (int j = 0; j < 2; ++j)
                    acc[i][j] = __builtin_amdgcn_mfma_f32_16x16x32_bf16(af[i], bfr[j], acc[i][j], 0, 0, 0);
        }
        p ^= 1;
    }

    const int half = N >> 1;
    #pragma unroll
    for (int i = 0; i < 4; ++i) {
        #pragma unroll
        for (int j = 0; j < 2; ++j) {
            int col = n0 + wn + j * 16 + lm;
            #pragma unroll
            for (int r = 0; r < 4; ++r) {
                int row = m0 + wm + i * 16 + quad * 4 + r;
                float v = acc[i][j][r];
                if (EPI == 2) {
                    ((float*)C0)[(size_t)row * N + col] = v;
                } else {
                    if (col < half) {
                        ((unsigned short*)C0)[(size_t)row * half + col] = f2bf(v);
                    } else {
                        float s = v / (1.f + __expf(-v));
                        ((unsigned short*)C1)[(size_t)row * half + col - half] = f2bf(s);
                    }
                }
            }
        }
    }
}

// ---- fused dt+xproj GEMM: BK=32, R14 structure, 24KB LDS (6 blocks/CU) ----
// Grid (32, 25): cols 0..1599. B rows <1536 from dtT, >=1536 from xpT
// (clamped to 1567; cols >=1568 computed but discarded). Per-thread B base
// hoisted (loop-invariant). Epilogue: col<1536 -> bf16 softplus(v+bias) dlt;
// 1536<=col<1568 -> f32 BC[row*32 + col-1536].
__global__ __launch_bounds__(256) void gemm_fused_kernel(
    const unsigned short* __restrict__ A, const unsigned short* __restrict__ Bt,
    const unsigned short* __restrict__ Bt2,
    unsigned short* __restrict__ C0, float* __restrict__ C1,
    const float* __restrict__ biasf, int M, int K)
{
    __shared__ __align__(16) unsigned short As[2][128 * 32];   // 16 KB
    __shared__ __align__(16) unsigned short Bs[2][64 * 32];    // 8 KB
    const int t    = threadIdx.x;
    const int m0   = blockIdx.x * 128;
    const int n0   = blockIdx.y * 64;
    const int w    = t >> 6;
    const int lane = t & 63;
    const int wm   = (w >> 1) * 64, wn = (w & 1) * 32;
    const int lm   = lane & 15, quad = lane >> 4;
    const int srow = lane >> 2;
    const int sg   = lane & 3;

    // hoisted loop-invariant staging bases
    const int arow0 = w * 32 + srow;
    const int arow1 = w * 32 + 16 + srow;
    const int akg0  = (sg - (arow0 >> 1)) & 3;
    const int akg1  = (sg - (arow1 >> 1)) & 3;
    const int brow  = w * 16 + srow;
    const int bkg   = (sg - (brow >> 1)) & 3;
    const int gr    = n0 + brow;
    const unsigned short* aB0 = &A[(size_t)(m0 + arow0) * K + akg0 * 8];
    const unsigned short* aB1 = &A[(size_t)(m0 + arow1) * K + akg1 * 8];
    const unsigned short* bB  = (gr < 1536)
        ? &Bt[(size_t)gr * K + bkg * 8]
        : &Bt2[(size_t)(((gr < 1567) ? gr : 1567) - 1536) * K + bkg * 8];

    f32x4 acc[4][2] = {};

    auto stage = [&](int k0, int q) {
        async_cp16((glob_us*)(aB0 + k0), (lds_us*)&As[q][(w * 32) * 32]);
        async_cp16((glob_us*)(aB1 + k0), (lds_us*)&As[q][(w * 32 + 16) * 32]);
        async_cp16((glob_us*)(bB  + k0), (lds_us*)&Bs[q][(w * 16) * 32]);
    };

    stage(0, 0);

    int p = 0;
    for (int k0 = 0; k0 < K; k0 += 32) {
        __syncthreads();
        if (k0 + 32 < K) stage(k0 + 32, p ^ 1);
        bf16x8 af[4], bfr[2];
        #pragma unroll
        for (int i = 0; i < 4; ++i) {
            int row = wm + i * 16 + lm;
            int g   = (quad + (row >> 1)) & 3;
            af[i] = *(const bf16x8*)&As[p][row * 32 + g * 8];
        }
        #pragma unroll
        for (int j = 0; j < 2; ++j) {
            int row = wn + j * 16 + lm;
            int g   = (quad + (row >> 1)) & 3;
            bfr[j] = *(const bf16x8*)&Bs[p][row * 32 + g * 8];
        }
        #pragma unroll
        for (int i = 0; i < 4; ++i)
            #pragma unroll
            for (int j = 0; j < 2; ++j)
                acc[i][j] = __builtin_amdgcn_mfma_f32_16x16x32_bf16(af[i], bfr[j], acc[i][j], 0, 0, 0);
        p ^= 1;
    }

    #pragma unroll
    for (int i = 0; i < 4; ++i) {
        #pragma unroll
        for (int j = 0; j < 2; ++j) {
            int col = n0 + wn + j * 16 + lm;
            #pragma unroll
            for (int r = 0; r < 4; ++r) {
                int row = m0 + wm + i * 16 + quad * 4 + r;
                float v = acc[i][j][r];
                if (col < 1536) {
                    v += biasf[col];
                    float sp = (v > 20.f) ? v : log1pf(__expf(v));
                    C0[(size_t)row * 1536 + col] = f2bf(sp);
                } else if (col < 1568) {
                    C1[(size_t)row * 32 + (col - 1536)] = v;
                }
            }
        }
    }
}

// ---- depthwise conv3 + bias + SiLU, 8 d/thread, plane weights ----
__global__ __launch_bounds__(256) void conv_silu_kernel(
    const unsigned short* __restrict__ xcpre, const float* __restrict__ cwf,
    const float* __restrict__ cbf, unsigned short* __restrict__ xcb)
{
    const float* cw0 = cwf;
    const float* cw1 = cwf + DINNER;
    const float* cw2 = cwf + 2 * DINNER;
    size_t idx = ((size_t)blockIdx.x * 256 + threadIdx.x) * 8;
    int d8  = (int)(idx % DINNER);
    int row = (int)(idx / DINNER);
    int l   = row % SEQL;
    size_t base = (size_t)row * DINNER + d8;
    uint4 zero = {0, 0, 0, 0};
    uint4 xm = (l > 0)        ? *(const uint4*)&xcpre[base - DINNER] : zero;
    uint4 x0 = *(const uint4*)&xcpre[base];
    uint4 xp = (l < SEQL - 1) ? *(const uint4*)&xcpre[base + DINNER] : zero;
    float4 c0a = *(const float4*)&cw0[d8], c0b = *(const float4*)&cw0[d8 + 4];
    float4 c1a = *(const float4*)&cw1[d8], c1b = *(const float4*)&cw1[d8 + 4];
    float4 c2a = *(const float4*)&cw2[d8], c2b = *(const float4*)&cw2[d8 + 4];
    float4 cba = *(const float4*)&cbf[d8], cbb = *(const float4*)&cbf[d8 + 4];
    const unsigned* mw = (const unsigned*)&xm;
    const unsigned* zw = (const unsigned*)&x0;
    const unsigned* pw = (const unsigned*)&xp;
    float w0[8] = {c0a.x, c0a.y, c0a.z, c0a.w, c0b.x, c0b.y, c0b.z, c0b.w};
    float w1[8] = {c1a.x, c1a.y, c1a.z, c1a.w, c1b.x, c1b.y, c1b.z, c1b.w};
    float w2[8] = {c2a.x, c2a.y, c2a.z, c2a.w, c2b.x, c2b.y, c2b.z, c2b.w};
    float bb[8] = {cba.x, cba.y, cba.z, cba.w, cbb.x, cbb.y, cbb.z, cbb.w};
    unsigned short out[8];
    #pragma unroll
    for (int k = 0; k < 8; ++k) {
        unsigned wm_ = mw[k >> 1], wz = zw[k >> 1], wp = pw[k >> 1];
        float a = (k & 1) ? bfhi(wm_) : bflo(wm_);
        float c = (k & 1) ? bfhi(wz)  : bflo(wz);
        float e = (k & 1) ? bfhi(wp)  : bflo(wp);
        float acc = bb[k] + a * w0[k] + c * w1[k] + e * w2[k];
        float s = acc / (1.f + __expf(-acc));
        out[k] = f2bf(s);
    }
    *(uint4*)&xcb[base] = *(uint4*)out;
}

// ====== chunked scan, q-split x 2-d-per-thread, register ping-pong (R23) ======
struct GrpA { unsigned dv2[4], xv2[4]; f32x4 Bv[4]; };
struct GrpC { unsigned dv2[4], xv2[4]; f32x4 Bv[4], Cv[4]; };

__device__ __forceinline__ void ldA(GrpA& gp, const unsigned short* pd,
    const unsigned short* px, const float* pbc, int l) {
    #pragma unroll
    for (int j = 0; j < 4; ++j) {
        size_t o = (size_t)(l + j) * DINNER;
        gp.dv2[j] = *(const unsigned*)&pd[o];
        gp.xv2[j] = *(const unsigned*)&px[o];
        gp.Bv[j]  = *(const f32x4*)&pbc[(size_t)(l + j) * 32];
    }
}
__device__ __forceinline__ void ldC(GrpC& gp, const unsigned short* pd,
    const unsigned short* px, const float* pbc, int l) {
    #pragma unroll
    for (int j = 0; j < 4; ++j) {
        size_t o = (size_t)(l + j) * DINNER;
        gp.dv2[j] = *(const unsigned*)&pd[o];
        gp.xv2[j] = *(const unsigned*)&px[o];
        gp.Bv[j]  = *(const f32x4*)&pbc[(size_t)(l + j) * 32];
        gp.Cv[j]  = *(const f32x4*)&pbc[(size_t)(l + j) * 32 + 16];
    }
}
__device__ __forceinline__ void stepA(const GrpA& gp, const f32x4 A2a,
    const f32x4 A2b, f32x4& h0, f32x4& h1, float& sdv0, float& sdv1) {
    #pragma unroll
    for (int j = 0; j < 4; ++j) {
        float dv0 = bflo(gp.dv2[j]), dv1 = bfhi(gp.dv2[j]);
        float xv0 = bflo(gp.xv2[j]), xv1 = bfhi(gp.xv2[j]);
        sdv0 += dv0; sdv1 += dv1;
        f32x4 Bv = gp.Bv[j];
        f32x4 e0, e1;
        e0[0] = __builtin_amdgcn_exp2f(dv0 * A2a[0]);
        e0[1] = __builtin_amdgcn_exp2f(dv0 * A2a[1]);
        e0[2] = __builtin_amdgcn_exp2f(dv0 * A2a[2]);
        e0[3] = __builtin_amdgcn_exp2f(dv0 * A2a[3]);
        e1[0] = __builtin_amdgcn_exp2f(dv1 * A2b[0]);
        e1[1] = __builtin_amdgcn_exp2f(dv1 * A2b[1]);
        e1[2] = __builtin_amdgcn_exp2f(dv1 * A2b[2]);
        e1[3] = __builtin_amdgcn_exp2f(dv1 * A2b[3]);
        h0 = e0 * h0 + (dv0 * xv0) * Bv;
        h1 = e1 * h1 + (dv1 * xv1) * Bv;
    }
}

__global__ __launch_bounds__(256) void scan_phase_a(
    const unsigned short* __restrict__ dlt, const unsigned short* __restrict__ xcb,
    const float* __restrict__ BC, const float* __restrict__ A_log_f,
    unsigned short* __restrict__ P, float* __restrict__ S)
{
    const int t   = threadIdx.x;
    const int q   = t & 3;
    const int dpl = t >> 2;                       // 0..63
    const int bid = blockIdx.x;
    const int dg  = bid % 12;
    const int cc  = (bid / 12) % NCHUNK;
    const int b   = bid / (12 * NCHUNK);
    const int d   = (dg * 64 + dpl) * 2;
    f32x4 A2a = *(const f32x4*)&A_log_f[d * 16 + q * 4];
    f32x4 A2b = *(const f32x4*)&A_log_f[(d + 1) * 16 + q * 4];
    f32x4 h0 = (f32x4){0.f, 0.f, 0.f, 0.f};
    f32x4 h1 = (f32x4){0.f, 0.f, 0.f, 0.f};
    float sdv0 = 0.f, sdv1 = 0.f;
    const int row0 = b * SEQL + cc * CHLEN;
    const unsigned short* pd = dlt + (size_t)row0 * DINNER + d;
    const unsigned short* px = xcb + (size_t)row0 * DINNER + d;
    const float* pbc = BC + (size_t)row0 * 32 + q * 4;

    GrpA ga, gb;
    ldA(ga, pd, px, pbc, 0);
    for (int l0 = 0; l0 < CHLEN; l0 += 8) {
        ldA(gb, pd, px, pbc, l0 + 4);
        stepA(ga, A2a, A2b, h0, h1, sdv0, sdv1);
        if (l0 + 8 < CHLEN) ldA(ga, pd, px, pbc, l0 + 8);
        stepA(gb, A2a, A2b, h0, h1, sdv0, sdv1);
    }

    size_t idx = (((size_t)(b * NCHUNK + cc)) * DINNER + d) * 16 + q * 4;
    *(f32x4*)&S[idx] = h0;
    *(f32x4*)&S[idx + 16] = h1;
    ushort4 p0, p1;
    p0.x = f2bf(__builtin_amdgcn_exp2f(sdv0 * A2a[0]));
    p0.y = f2bf(__builtin_amdgcn_exp2f(sdv0 * A2a[1]));
    p0.z = f2bf(__builtin_amdgcn_exp2f(sdv0 * A2a[2]));
    p0.w = f2bf(__builtin_amdgcn_exp2f(sdv0 * A2a[3]));
    p1.x = f2bf(__builtin_amdgcn_exp2f(sdv1 * A2b[0]));
    p1.y = f2bf(__builtin_amdgcn_exp2f(sdv1 * A2b[1]));
    p1.z = f2bf(__builtin_amdgcn_exp2f(sdv1 * A2b[2]));
    p1.w = f2bf(__builtin_amdgcn_exp2f(sdv1 * A2b[3]));
    *(ushort4*)&P[idx] = p0;
    *(ushort4*)&P[idx + 16] = p1;
}

__global__ __launch_bounds__(256) void scan_combine(
    const unsigned short* __restrict__ P, float* __restrict__ S)
{
    int t = blockIdx.x * 256 + threadIdx.x;            // < 2*1536*16
    int b = t / (DINNER * NSTATE);
    int dn = t % (DINNER * NSTATE);
    const size_t stride = (size_t)(DINNER * NSTATE);
    size_t idx = (size_t)b * NCHUNK * stride + dn;
    float Pv = bf2f(P[idx]);
    float Sv = S[idx];
    float H = 0.f;
    for (int c = 0; c < NCHUNK; ++c) {
        float Pn = 0.f, Sn = 0.f;
        if (c + 1 < NCHUNK) {                  // prefetch next chunk
            Pn = bf2f(P[idx + stride]);
            Sn = S[idx + stride];
        }
        S[idx] = H;                 // Hin for chunk c
        H = Pv * H + Sv;
        Pv = Pn; Sv = Sn;
        idx += stride;
    }
}

__global__ __launch_bounds__(256) void scan_phase_c(
    const unsigned short* __restrict__ dlt, const unsigned short* __restrict__ xcb,
    const float* __restrict__ BC, const unsigned short* __restrict__ zg,
    const float* __restrict__ A_log_f, const float* __restrict__ D_f,
    const float* __restrict__ Hin, unsigned short* __restrict__ yg)
{
    const int t   = threadIdx.x;
    const int q   = t & 3;
    const int dpl = t >> 2;
    const int bid = blockIdx.x;
    const int dg  = bid % 12;
    const int cc  = (bid / 12) % NCHUNK;
    const int b   = bid / (12 * NCHUNK);
    const int d   = (dg * 64 + dpl) * 2;
    f32x4 A2a = *(const f32x4*)&A_log_f[d * 16 + q * 4];
    f32x4 A2b = *(const f32x4*)&A_log_f[(d + 1) * 16 + q * 4];
    size_t hidx = (((size_t)(b * NCHUNK + cc)) * DINNER + d) * 16 + q * 4;
    f32x4 h0 = *(const f32x4*)&Hin[hidx];
    f32x4 h1 = *(const f32x4*)&Hin[hidx + 16];
    const float Dd0 = D_f[d], Dd1 = D_f[d + 1];
    const int row0 = b * SEQL + cc * CHLEN;
    const unsigned short* pd = dlt + (size_t)row0 * DINNER + d;
    const unsigned short* px = xcb + (size_t)row0 * DINNER + d;
    const unsigned short* pz = zg  + (size_t)row0 * DINNER + d;
    unsigned short* py = yg + (size_t)row0 * DINNER + d;
    const float* pbc = BC + (size_t)row0 * 32 + q * 4;

    GrpC ga, gb;
    auto stepC = [&](const GrpC& gp, int l) {
        #pragma unroll
        for (int j = 0; j < 4; ++j) {
            float dv0 = bflo(gp.dv2[j]), dv1 = bfhi(gp.dv2[j]);
            float xv0 = bflo(gp.xv2[j]), xv1 = bfhi(gp.xv2[j]);
            f32x4 Bv = gp.Bv[j], Cv = gp.Cv[j];
            f32x4 e0, e1;
            e0[0] = __builtin_amdgcn_exp2f(dv0 * A2a[0]);
            e0[1] = __builtin_amdgcn_exp2f(dv0 * A2a[1]);
            e0[2] = __builtin_amdgcn_exp2f(dv0 * A2a[2]);
            e0[3] = __builtin_amdgcn_exp2f(dv0 * A2a[3]);
            e1[0] = __builtin_amdgcn_exp2f(dv1 * A2b[0]);
            e1[1] = __builtin_amdgcn_exp2f(dv1 * A2b[1]);
            e1[2] = __builtin_amdgcn_exp2f(dv1 * A2b[2]);
            e1[3] = __builtin_amdgcn_exp2f(dv1 * A2b[3]);
            h0 = e0 * h0 + (dv0 * xv0) * Bv;
            h1 = e1 * h1 + (dv1 * xv1) * Bv;
            f32x4 y0v = h0 * Cv;
            f32x4 y1v = h1 * Cv;
            float y0 = quad_reduce(y0v[0] + y0v[1] + y0v[2] + y0v[3]);
            float y1 = quad_reduce(y1v[0] + y1v[1] + y1v[2] + y1v[3]);
            if (j == q) {                      // rotated store: lane q owns step j
                unsigned zp = *(const unsigned*)&pz[(size_t)(l + j) * DINNER];
                ushort2 o;
                o.x = f2bf((y0 + Dd0 * xv0) * bflo(zp));
                o.y = f2bf((y1 + Dd1 * xv1) * bfhi(zp));
                *(ushort2*)&py[(size_t)(l + j) * DINNER] = o;
            }
        }
    };

    ldC(ga, pd, px, pbc, 0);
    for (int l0 = 0; l0 < CHLEN; l0 += 8) {
        ldC(gb, pd, px, pbc, l0 + 4);
        stepC(ga, l0);
        if (l0 + 8 < CHLEN) ldC(ga, pd, px, pbc, l0 + 8);
        stepC(gb, l0 + 4);
    }
}

__global__ void guard_kernel(float* out, int code)
{
    if (threadIdx.x == 0 && blockIdx.x == 0 && code) out[0] = (float)code;
}

extern "C" void kernel_launch(void* const* d_in, const int* in_sizes, int n_in,
                              void* d_out, int out_size, void* d_ws, size_t ws_size,
                              hipStream_t stream) {
    static const int EXPECTED[10] = {3145728, 2359296, 4608, 1536, 49152,
                                     2359296, 1536, 24576, 1536, 1179648};
    bool ok = (n_in == 10);
    if (ok) for (int i = 0; i < 10; ++i) ok = ok && (in_sizes[i] == EXPECTED[i]);
    int code = 0;
    if (!ok) code = 2000;
    else if (ws_size < 67895296ULL) code = 3000;
    if (code) { guard_kernel<<<1, 64, 0, stream>>>((float*)d_out, code); return; }

    const void* x       = d_in[0];
    const void* in_w    = d_in[1];
    const void* conv_w  = d_in[2];
    const void* conv_b  = d_in[3];
    const void* xproj_w = d_in[4];
    const void* dt_w    = d_in[5];
    const void* dt_b    = d_in[6];
    const void* A_log   = d_in[7];
    const void* Dvec    = d_in[8];
    const void* out_w   = d_in[9];

    char* ws = (char*)d_ws;
    float* conv_w_f = (float*)(ws + 0);        // 3 planes x 1536 f32 (18432 B)
    float* conv_b_f = (float*)(ws + 18432);    // 1536
    float* dt_b_f   = (float*)(ws + 24576);    // 1536
    float* A_log_f  = (float*)(ws + 30720);    // 24576 (holds A2 = -exp(A_log)*log2e)
    float* D_f      = (float*)(ws + 129024);   // 1536
    // legacy f32 xproj copy still written by prep at [135168, 331776)
    unsigned short* xpT   = (unsigned short*)(ws + 331776);    // [32][1536] bf16, ends 430080
    unsigned short* xb    = (unsigned short*)(ws + 524288);    // [4096][768]  (dead after gemm1)
    unsigned short* inT   = (unsigned short*)(ws + 6815744);   // [3072][768]  (dead after gemm1)
    unsigned short* yg    = (unsigned short*)(ws + 524288);    // [4096][1536] alias xb+inT
    unsigned short* dtT   = (unsigned short*)(ws + 13107200);  // [1536][1536]
    unsigned short* outT  = (unsigned short*)(ws + 17825792);  // [768][1536]
    unsigned short* xcpre = (unsigned short*)(ws + 20185088);  // [4096][1536] (dead after conv)
    unsigned short* dlt   = xcpre;                             // alias (gemm2 out)
    float*          BC    = (float*)(ws + 32768000);           // [4096][32]
    unsigned short* zg    = (unsigned short*)(ws + 33292288);  // [4096][1536] silu(z)
    unsigned short* xcb   = (unsigned short*)(ws + 45875200);  // [4096][1536]
    float*          scanS = (float*)(ws + 58458112);           // [2][32][1536][16] f32 6.29MB
    unsigned short* scanP = (unsigned short*)(ws + 64749568);  // same shape bf16   3.15MB

    prep_kernel<<<3306, 256, 0, stream>>>(x, in_w, conv_w, conv_b, xproj_w, dt_w,
                                          dt_b, A_log, Dvec, out_w,
                                          xb, inT, dtT, outT, xpT, (float*)ws);

    gemm_kernel<3><<<dim3(32, 48), 256, 0, stream>>>(xb, inT, (void*)xcpre,
                                                     (void*)zg, nullptr, 4096, 3072, 768);
    conv_silu_kernel<<<(4096 * DINNER / 8) / 256, 256, 0, stream>>>(xcpre, conv_w_f, conv_b_f, xcb);
    gemm_fused_kernel<<<dim3(32, 25), 256, 0, stream>>>(xcb, dtT, xpT, dlt, BC,
                                                        dt_b_f, 4096, 1536);
    scan_phase_a<<<768, 256, 0, stream>>>(dlt, xcb, BC, A_log_f, scanP, scanS);
    scan_combine<<<192, 256, 0, stream>>>(scanP, scanS);
    scan_phase_c<<<768, 256, 0, stream>>>(dlt, xcb, BC, zg, A_log_f, D_f, scanS, yg);
    gemm_kernel<2><<<dim3(32, 12), 256, 0, stream>>>(yg, outT, d_out,
                                                     nullptr, nullptr, 4096, 768, 1536);
}